// Round 2
// baseline (853.249 us; speedup 1.0000x reference)
//
#include <hip/hip_runtime.h>
#include <stdint.h>

#define B_    16
#define N_    2500

typedef unsigned short u16;
typedef __attribute__((ext_vector_type(8))) short bf16x8;
typedef __attribute__((ext_vector_type(4))) float f32x4;

__device__ __forceinline__ u16 f2bf(float f) {
  unsigned u = __float_as_uint(f);
  return (u16)((u + 0x7fffu + ((u >> 16) & 1u)) >> 16);
}

__device__ __forceinline__ void unpack8(uint4 w, float* f) {
  f[0] = __uint_as_float(w.x << 16);
  f[1] = __uint_as_float(w.x & 0xffff0000u);
  f[2] = __uint_as_float(w.y << 16);
  f[3] = __uint_as_float(w.y & 0xffff0000u);
  f[4] = __uint_as_float(w.z << 16);
  f[5] = __uint_as_float(w.z & 0xffff0000u);
  f[6] = __uint_as_float(w.w << 16);
  f[7] = __uint_as_float(w.w & 0xffff0000u);
}

__device__ __forceinline__ float sigm(float x) {
  return __builtin_amdgcn_rcpf(1.f + __expf(-x));
}

// ---------- kernel A: nf1 = relu(bn(nW1 @ node)), bf16, transposed [b*N+n][c] ----------
__global__ __launch_bounds__(256) void k_nf1(
    const float* __restrict__ node, const float* __restrict__ W,
    const float* __restrict__ bia, const float* __restrict__ sc,
    const float* __restrict__ sh, u16* __restrict__ nf1b) {
  int tid = blockIdx.x * 256 + threadIdx.x;   // 640,000 threads exactly
  int og  = tid & 15;
  int bn  = tid >> 4;
  int b = bn / N_;
  int n = bn - b * N_;
  const float* xp = node + (size_t)(b * 64) * N_ + n;
  int o0 = og * 4;
  const float* w0 = W + (size_t)(o0 + 0) * 64;
  const float* w1 = W + (size_t)(o0 + 1) * 64;
  const float* w2 = W + (size_t)(o0 + 2) * 64;
  const float* w3 = W + (size_t)(o0 + 3) * 64;
  float a0 = 0.f, a1 = 0.f, a2 = 0.f, a3 = 0.f;
#pragma unroll 8
  for (int c = 0; c < 64; ++c) {
    float x = xp[(size_t)c * N_];
    a0 = fmaf(w0[c], x, a0);
    a1 = fmaf(w1[c], x, a1);
    a2 = fmaf(w2[c], x, a2);
    a3 = fmaf(w3[c], x, a3);
  }
  float r0 = fmaxf(fmaf(sc[o0 + 0], a0 + bia[o0 + 0], sh[o0 + 0]), 0.f);
  float r1 = fmaxf(fmaf(sc[o0 + 1], a1 + bia[o0 + 1], sh[o0 + 1]), 0.f);
  float r2 = fmaxf(fmaf(sc[o0 + 2], a2 + bia[o0 + 2], sh[o0 + 2]), 0.f);
  float r3 = fmaxf(fmaf(sc[o0 + 3], a3 + bia[o0 + 3], sh[o0 + 3]), 0.f);
  uint2 st;
  st.x = (unsigned)f2bf(r0) | ((unsigned)f2bf(r1) << 16);
  st.y = (unsigned)f2bf(r2) | ((unsigned)f2bf(r3) << 16);
  *(uint2*)&nf1b[(size_t)bn * 64 + o0] = st;
}

// ---------- kernel B: fused MFMA message passing ----------
// 512 threads = 8 waves; one node per wave per iteration; 4 iterations.
__global__ __launch_bounds__(512, 4) void k_fused(
    const float* __restrict__ node, const float* __restrict__ wfeat,
    const int* __restrict__ etype, const int* __restrict__ nn_idx,
    const u16* __restrict__ nf1b,
    const float* __restrict__ wW1, const float* __restrict__ wb1,
    const float* __restrict__ ws1, const float* __restrict__ wsh1,
    const float* __restrict__ theta, const float* __restrict__ theta_b,
    const float* __restrict__ gateW, const float* __restrict__ gate_b,
    const float* __restrict__ edgeW, const float* __restrict__ edge_b,
    const float* __restrict__ nW2, const float* __restrict__ nb2,
    const float* __restrict__ ns2, const float* __restrict__ nsh2,
    const float* __restrict__ wW2, const float* __restrict__ wb2,
    const float* __restrict__ ws2, const float* __restrict__ wsh2,
    float* __restrict__ out_nf, float* __restrict__ out_wf) {

  // weights in LDS, bf16, padded strides (2-way bank conflicts max)
  __shared__ __align__(16) u16 th_s[192 * 72];   // theta rows (t*64+o), stride 72
  __shared__ __align__(16) u16 nW2_s[64 * 72];
  __shared__ __align__(16) u16 gW_s[64 * 40];
  __shared__ __align__(16) u16 eW_s[32 * 104];   // edgeW 32x96, stride 104
  __shared__ __align__(16) u16 wW1_s[32 * 40];
  __shared__ __align__(16) u16 wW2_s[32 * 40];
  __shared__ __align__(16) float tb_s[192];
  __shared__ __align__(16) float gb_s[64];
  __shared__ __align__(16) float eb_s[32];
  __shared__ __align__(16) float ws1_s[32], wb1_s[32], wsh1_s[32];
  __shared__ __align__(16) float ns2_s[64], nb2_s[64], nsh2_s[64];
  __shared__ __align__(16) float ws2_s[32], wb2_s[32], wsh2_s[32];
  // per-wave tiles (wave-internal use only, no block barriers in node loop)
  __shared__ __align__(16) u16 wtile[8][16 * 40];  // [edge][ch], stride 40
  __shared__ __align__(16) float nout_s[8][64];

  const int tid = threadIdx.x;

  for (int p = tid; p < 12288; p += 512) th_s[(p >> 6) * 72 + (p & 63)] = f2bf(theta[p]);
  for (int p = tid; p < 4096;  p += 512) nW2_s[(p >> 6) * 72 + (p & 63)] = f2bf(nW2[p]);
  for (int p = tid; p < 2048;  p += 512) gW_s[(p >> 5) * 40 + (p & 31)] = f2bf(gateW[p]);
  for (int p = tid; p < 3072;  p += 512) eW_s[(p / 96) * 104 + (p % 96)] = f2bf(edgeW[p]);
  for (int p = tid; p < 1024;  p += 512) {
    wW1_s[(p >> 5) * 40 + (p & 31)] = f2bf(wW1[p]);
    wW2_s[(p >> 5) * 40 + (p & 31)] = f2bf(wW2[p]);
  }
  if (tid < 192) tb_s[tid] = theta_b[tid];
  if (tid < 64) { gb_s[tid] = gate_b[tid]; ns2_s[tid] = ns2[tid]; nb2_s[tid] = nb2[tid]; nsh2_s[tid] = nsh2[tid]; }
  if (tid < 32) {
    eb_s[tid] = edge_b[tid];
    ws1_s[tid] = ws1[tid]; wb1_s[tid] = wb1[tid]; wsh1_s[tid] = wsh1[tid];
    ws2_s[tid] = ws2[tid]; wb2_s[tid] = wb2[tid]; wsh2_s[tid] = wsh2[tid];
  }
  __syncthreads();

  const int l  = tid & 63;
  const int wv = tid >> 6;
  const int el = l & 15;   // edge (MFMA column)
  const int kg = l >> 4;   // K-group
  u16* wt = &wtile[wv][0];
  const f32x4 z4 = {0.f, 0.f, 0.f, 0.f};

  for (int it = 0; it < 4; ++it) {
    const int nodeid = blockIdx.x * 32 + it * 8 + wv;
    const int b = nodeid / N_;
    const int n = nodeid - b * N_;
    const int ebase = nodeid * 16;

    const int idx = nn_idx[ebase + el];
    const int et  = etype[ebase + el];

    // ---- nb B-fragments straight from the gather (bf16 nf1) ----
    const bf16x8* nbp = (const bf16x8*)(nf1b + (((size_t)b * N_ + idx) * 64 + kg * 8));
    bf16x8 nbf0 = nbp[0];   // channels kg*8..+7
    bf16x8 nbf1 = nbp[4];   // channels 32+kg*8..+7

    // ---- x B-fragment from wfeat ----
    union UF { bf16x8 v; u16 u[8]; uint4 q; } xf;
    const float* wfp = wfeat + (((size_t)b * 32 + kg * 8) * N_ + n) * 16 + el;
#pragma unroll
    for (int j = 0; j < 8; ++j) xf.u[j] = f2bf(wfp[(size_t)j * N_ * 16]);

    // ---- wf1 = relu(bn(wW1 @ x)) : 2 MFMAs ----
    f32x4 wc[2];
#pragma unroll
    for (int mt = 0; mt < 2; ++mt) {
      bf16x8 a = *(const bf16x8*)&wW1_s[(mt * 16 + el) * 40 + kg * 8];
      wc[mt] = __builtin_amdgcn_mfma_f32_16x16x32_bf16(a, xf.v, z4, 0, 0, 0);
    }
#pragma unroll
    for (int mt = 0; mt < 2; ++mt) {
      int ob = mt * 16 + kg * 4;
      float4 s  = *(const float4*)&ws1_s[ob];
      float4 bb = *(const float4*)&wb1_s[ob];
      float4 sh = *(const float4*)&wsh1_s[ob];
      u16 h0 = f2bf(fmaxf(fmaf(s.x, wc[mt][0] + bb.x, sh.x), 0.f));
      u16 h1 = f2bf(fmaxf(fmaf(s.y, wc[mt][1] + bb.y, sh.y), 0.f));
      u16 h2 = f2bf(fmaxf(fmaf(s.z, wc[mt][2] + bb.z, sh.z), 0.f));
      u16 h3 = f2bf(fmaxf(fmaf(s.w, wc[mt][3] + bb.w, sh.w), 0.f));
      uint2 d;
      d.x = (unsigned)h0 | ((unsigned)h1 << 16);
      d.y = (unsigned)h2 | ((unsigned)h3 << 16);
      *(uint2*)&wt[el * 40 + ob] = d;   // transposed: [edge][channel]
    }
    bf16x8 wff = *(const bf16x8*)&wt[el * 40 + kg * 8];  // wf1 as B-frag

    // ---- msg: 3 etypes x 4 M-tiles x 2 K-steps = 24 MFMAs, mask folded into B ----
    f32x4 macc[4] = {z4, z4, z4, z4};
    union UF nb0u, nb1u;
    nb0u.v = nbf0; nb1u.v = nbf1;
#pragma unroll
    for (int t = 0; t < 3; ++t) {
      unsigned msk = (et == t) ? 0xffffffffu : 0u;
      union UF b0, b1;
      b0.q.x = nb0u.q.x & msk; b0.q.y = nb0u.q.y & msk;
      b0.q.z = nb0u.q.z & msk; b0.q.w = nb0u.q.w & msk;
      b1.q.x = nb1u.q.x & msk; b1.q.y = nb1u.q.y & msk;
      b1.q.z = nb1u.q.z & msk; b1.q.w = nb1u.q.w & msk;
      const u16* thp = &th_s[(t * 64 + el) * 72 + kg * 8];
#pragma unroll
      for (int mt = 0; mt < 4; ++mt) {
        bf16x8 a0 = *(const bf16x8*)&thp[mt * 16 * 72];
        bf16x8 a1 = *(const bf16x8*)&thp[mt * 16 * 72 + 32];
        macc[mt] = __builtin_amdgcn_mfma_f32_16x16x32_bf16(a0, b0.v, macc[mt], 0, 0, 0);
        macc[mt] = __builtin_amdgcn_mfma_f32_16x16x32_bf16(a1, b1.v, macc[mt], 0, 0, 0);
      }
    }

    // ---- edge conv: w_out_pre = edgeW @ [wf1; nb] : 6 MFMAs ----
    f32x4 eacc[2];
#pragma unroll
    for (int mt = 0; mt < 2; ++mt) {
      const u16* ep = &eW_s[(mt * 16 + el) * 104 + kg * 8];
      bf16x8 a0 = *(const bf16x8*)&ep[0];
      bf16x8 a1 = *(const bf16x8*)&ep[32];
      bf16x8 a2 = *(const bf16x8*)&ep[64];
      f32x4 acc = __builtin_amdgcn_mfma_f32_16x16x32_bf16(a0, wff, z4, 0, 0, 0);
      acc = __builtin_amdgcn_mfma_f32_16x16x32_bf16(a1, nbf0, acc, 0, 0, 0);
      acc = __builtin_amdgcn_mfma_f32_16x16x32_bf16(a2, nbf1, acc, 0, 0, 0);
      eacc[mt] = acc;
    }

    // ---- gate (4 MFMAs) + combine + mean over edges (butterfly in 16-lane groups) ----
#pragma unroll
    for (int mt = 0; mt < 4; ++mt) {
      bf16x8 ga = *(const bf16x8*)&gW_s[(mt * 16 + el) * 40 + kg * 8];
      f32x4 g = __builtin_amdgcn_mfma_f32_16x16x32_bf16(ga, wff, z4, 0, 0, 0);
      int ob = mt * 16 + kg * 4;
      float4 tb = *(const float4*)&tb_s[et * 64 + ob];
      float4 gb = *(const float4*)&gb_s[ob];
      float p0 = (macc[mt][0] + tb.x) * sigm(g[0] + gb.x);
      float p1 = (macc[mt][1] + tb.y) * sigm(g[1] + gb.y);
      float p2 = (macc[mt][2] + tb.z) * sigm(g[2] + gb.z);
      float p3 = (macc[mt][3] + tb.w) * sigm(g[3] + gb.w);
#pragma unroll
      for (int sft = 1; sft < 16; sft <<= 1) {
        p0 += __shfl_xor(p0, sft);
        p1 += __shfl_xor(p1, sft);
        p2 += __shfl_xor(p2, sft);
        p3 += __shfl_xor(p3, sft);
      }
      if (el == 0) {
        float4 r4;
        r4.x = fmaxf(p0 * 0.0625f, 0.f);
        r4.y = fmaxf(p1 * 0.0625f, 0.f);
        r4.z = fmaxf(p2 * 0.0625f, 0.f);
        r4.w = fmaxf(p3 * 0.0625f, 0.f);
        *(float4*)&nout_s[wv][ob] = r4;
      }
    }

    // ---- nf2 = relu(bn(nW2 @ n_out)) + node residual; lane l = out channel ----
    {
      float acc2 = 0.f;
#pragma unroll
      for (int cc = 0; cc < 8; ++cc) {
        uint4 wrow = *(const uint4*)&nW2_s[l * 72 + cc * 8];
        float w8[8];
        unpack8(wrow, w8);
        const float* np2 = &nout_s[wv][cc * 8];
#pragma unroll
        for (int j = 0; j < 8; ++j) acc2 = fmaf(w8[j], np2[j], acc2);
      }
      size_t noff = ((size_t)b * 64 + l) * N_ + n;
      float y = fmaxf(fmaf(ns2_s[l], acc2 + nb2_s[l], nsh2_s[l]), 0.f);
      out_nf[noff] = y + node[noff];
    }

    // ---- w_out = relu(edge_pre + edge_b) -> transposed LDS tile (overwrites wf1 tile) ----
#pragma unroll
    for (int mt = 0; mt < 2; ++mt) {
      int ob = mt * 16 + kg * 4;
      float4 eb4 = *(const float4*)&eb_s[ob];
      u16 h0 = f2bf(fmaxf(eacc[mt][0] + eb4.x, 0.f));
      u16 h1 = f2bf(fmaxf(eacc[mt][1] + eb4.y, 0.f));
      u16 h2 = f2bf(fmaxf(eacc[mt][2] + eb4.z, 0.f));
      u16 h3 = f2bf(fmaxf(eacc[mt][3] + eb4.w, 0.f));
      uint2 d;
      d.x = (unsigned)h0 | ((unsigned)h1 << 16);
      d.y = (unsigned)h2 | ((unsigned)h3 << 16);
      *(uint2*)&wt[el * 40 + ob] = d;
    }
    bf16x8 wof = *(const bf16x8*)&wt[el * 40 + kg * 8];

    // ---- wf2 = relu(bn(wW2 @ w_out)) + wfeat residual ----
    f32x4 fc[2];
#pragma unroll
    for (int mt = 0; mt < 2; ++mt) {
      bf16x8 a = *(const bf16x8*)&wW2_s[(mt * 16 + el) * 40 + kg * 8];
      fc[mt] = __builtin_amdgcn_mfma_f32_16x16x32_bf16(a, wof, z4, 0, 0, 0);
    }
#pragma unroll
    for (int mt = 0; mt < 2; ++mt) {
      int ob = mt * 16 + kg * 4;
      float4 s  = *(const float4*)&ws2_s[ob];
      float4 bb = *(const float4*)&wb2_s[ob];
      float4 sh = *(const float4*)&wsh2_s[ob];
      float sv[4] = {s.x, s.y, s.z, s.w};
      float bv[4] = {bb.x, bb.y, bb.z, bb.w};
      float hv[4] = {sh.x, sh.y, sh.z, sh.w};
#pragma unroll
      for (int r = 0; r < 4; ++r) {
        size_t a2 = (((size_t)b * 32 + ob + r) * N_ + n) * 16 + el;
        float y = fmaxf(fmaf(sv[r], fc[mt][r] + bv[r], hv[r]), 0.f);
        out_wf[a2] = y + wfeat[a2];
      }
    }
  }
}

extern "C" void kernel_launch(void* const* d_in, const int* in_sizes, int n_in,
                              void* d_out, int out_size, void* d_ws, size_t ws_size,
                              hipStream_t stream) {
  const float* node    = (const float*)d_in[0];
  const float* wfeat   = (const float*)d_in[1];
  const int*   etype   = (const int*)d_in[2];
  const int*   nn_idx  = (const int*)d_in[3];
  const float* nW1     = (const float*)d_in[4];
  const float* nb1     = (const float*)d_in[5];
  const float* ns1     = (const float*)d_in[6];
  const float* nsh1    = (const float*)d_in[7];
  const float* wW1     = (const float*)d_in[8];
  const float* wb1     = (const float*)d_in[9];
  const float* ws1     = (const float*)d_in[10];
  const float* wsh1    = (const float*)d_in[11];
  const float* theta   = (const float*)d_in[12];
  const float* theta_b = (const float*)d_in[13];
  const float* gateW   = (const float*)d_in[14];
  const float* gate_b  = (const float*)d_in[15];
  const float* edgeW   = (const float*)d_in[16];
  const float* edge_b  = (const float*)d_in[17];
  const float* nW2     = (const float*)d_in[18];
  const float* nb2     = (const float*)d_in[19];
  const float* ns2     = (const float*)d_in[20];
  const float* nsh2    = (const float*)d_in[21];
  const float* wW2     = (const float*)d_in[22];
  const float* wb2     = (const float*)d_in[23];
  const float* ws2     = (const float*)d_in[24];
  const float* wsh2    = (const float*)d_in[25];

  u16*   nf1b   = (u16*)d_ws;                           // 40000*64 bf16 = 5.12 MB
  float* out_nf = (float*)d_out;                        // (B,64,N,1)
  float* out_wf = (float*)d_out + (size_t)B_ * 64 * N_; // (B,32,N,16)

  k_nf1<<<2500, 256, 0, stream>>>(node, nW1, nb1, ns1, nsh1, nf1b);
  k_fused<<<1250, 512, 0, stream>>>(node, wfeat, etype, nn_idx, nf1b,
                                    wW1, wb1, ws1, wsh1,
                                    theta, theta_b, gateW, gate_b, edgeW, edge_b,
                                    nW2, nb2, ns2, nsh2, wW2, wb2, ws2, wsh2,
                                    out_nf, out_wf);
}

// Round 3
// 475.955 us; speedup vs baseline: 1.7927x; 1.7927x over previous
//
#include <hip/hip_runtime.h>
#include <stdint.h>

#define B_ 16
#define N_ 2500

typedef unsigned short u16;
typedef __attribute__((ext_vector_type(8))) short bf16x8;
typedef __attribute__((ext_vector_type(4))) float f32x4;

// XOR-swizzled slab addressing: u16 index within [32 nodes][16 k][32 ch]
#define SL(nl, k, ch) (((nl) << 9) + (((((k) << 5) + (ch))) ^ (((nl) & 7) << 3)))

__device__ __forceinline__ u16 f2bf(float f) {
  unsigned u = __float_as_uint(f);
  return (u16)((u + 0x7fffu + ((u >> 16) & 1u)) >> 16);
}
__device__ __forceinline__ float bf2f(u16 h) {
  return __uint_as_float(((unsigned)h) << 16);
}
__device__ __forceinline__ float sigm(float x) { return 1.f / (1.f + __expf(-x)); }

// ---------- kernel A: nf1 = relu(bn(nW1 @ node)) -> bf16 [b*N+n][64] ----------
// 256 threads = 64 consecutive bn x 4 channel-groups of 16. grid 625.
__global__ __launch_bounds__(256) void k_nf1(
    const float* __restrict__ node, const float* __restrict__ W,
    const float* __restrict__ bia, const float* __restrict__ sc,
    const float* __restrict__ sh, u16* __restrict__ nf1b) {
  const int n_l = threadIdx.x & 63;
  const int cg  = threadIdx.x >> 6;  // 0..3 (wave-uniform)
  const int bn  = blockIdx.x * 64 + n_l;
  const int b = bn / N_;
  const int n = bn - b * N_;
  const float* xp = node + (size_t)b * 64 * N_ + n;
  float acc[16];
#pragma unroll
  for (int o = 0; o < 16; ++o) acc[o] = 0.f;
  for (int c = 0; c < 64; ++c) {
    float x = xp[(size_t)c * N_];
    const float* wc = W + (size_t)(cg * 16) * 64 + c;
#pragma unroll
    for (int o = 0; o < 16; ++o) acc[o] = fmaf(wc[o * 64], x, acc[o]);
  }
  u16 st[16];
#pragma unroll
  for (int o = 0; o < 16; ++o) {
    int oc = cg * 16 + o;
    st[o] = f2bf(fmaxf(fmaf(sc[oc], acc[o] + bia[oc], sh[oc]), 0.f));
  }
  uint4 q0, q1;
  q0.x = (unsigned)st[0] | ((unsigned)st[1] << 16);
  q0.y = (unsigned)st[2] | ((unsigned)st[3] << 16);
  q0.z = (unsigned)st[4] | ((unsigned)st[5] << 16);
  q0.w = (unsigned)st[6] | ((unsigned)st[7] << 16);
  q1.x = (unsigned)st[8] | ((unsigned)st[9] << 16);
  q1.y = (unsigned)st[10] | ((unsigned)st[11] << 16);
  q1.z = (unsigned)st[12] | ((unsigned)st[13] << 16);
  q1.w = (unsigned)st[14] | ((unsigned)st[15] << 16);
  *(uint4*)&nf1b[(size_t)bn * 64 + cg * 16]     = q0;
  *(uint4*)&nf1b[(size_t)bn * 64 + cg * 16 + 8] = q1;
}

// ---------- kernel B: fused MFMA message passing, 3-phase ----------
__global__ __launch_bounds__(512, 4) void k_fused(
    const float* __restrict__ node, const float* __restrict__ wfeat,
    const int* __restrict__ etype, const int* __restrict__ nn_idx,
    const u16* __restrict__ nf1b,
    const float* __restrict__ wW1, const float* __restrict__ wb1,
    const float* __restrict__ ws1, const float* __restrict__ wsh1,
    const float* __restrict__ theta, const float* __restrict__ theta_b,
    const float* __restrict__ gateW, const float* __restrict__ gate_b,
    const float* __restrict__ edgeW, const float* __restrict__ edge_b,
    const float* __restrict__ nW2, const float* __restrict__ nb2,
    const float* __restrict__ ns2, const float* __restrict__ nsh2,
    const float* __restrict__ wW2, const float* __restrict__ wb2,
    const float* __restrict__ ws2, const float* __restrict__ wsh2,
    float* __restrict__ out_nf, float* __restrict__ out_wf) {

  __shared__ __align__(16) u16 th_p[24 * 64 * 8];   // theta frags, lane-packed, 24576 B
  __shared__ __align__(16) u16 eW_p[6 * 64 * 8];    // edgeW frags, 6144 B
  __shared__ __align__(16) u16 gW_p[4 * 64 * 8];    // gateW frags, 4096 B
  __shared__ __align__(16) float tb_s[192];
  __shared__ __align__(16) float gb_s[64], ns2_s[64], nb2_s[64], nsh2_s[64];
  __shared__ __align__(16) float eb_s[32], ws1_s[32], wb1_s[32], wsh1_s[32];
  __shared__ __align__(16) float ws2_s[32], wb2_s[32], wsh2_s[32];
  __shared__ __align__(16) float nout_s[32 * 68];   // 8704 B
  __shared__ __align__(16) u16 slab[32 * 512];      // 32768 B

  const int tid = threadIdx.x;

  // XCD-chunked bijective swizzle: nwg=1250, q=156, r=2
  {
  }
  const int pb  = blockIdx.x;
  const int xcd = pb & 7, sub = pb >> 3;
  const int lb  = (xcd < 2) ? (xcd * 157 + sub) : (2 * 157 + (xcd - 2) * 156 + sub);
  const int nbase = lb * 32;

  // ---- stage lane-packed weight fragments (u32 granularity) ----
  for (int q = tid; q < 6144; q += 512) {  // theta: f = t*8 + mt*2 + h
    int f = q >> 8, lane = (q >> 2) & 63, jp = q & 3;
    int t = f >> 3, mt = (f >> 1) & 3, h = f & 1;
    int el = lane & 15, kg = lane >> 4;
    const float* src = theta + ((size_t)t * 64 + mt * 16 + el) * 64 + h * 32 + kg * 8 + jp * 2;
    ((unsigned*)th_p)[q] = (unsigned)f2bf(src[0]) | ((unsigned)f2bf(src[1]) << 16);
  }
  for (int q = tid; q < 1536; q += 512) {  // edgeW: f = mt*3 + s
    int f = q >> 8, lane = (q >> 2) & 63, jp = q & 3;
    int mt = f / 3, s = f - mt * 3;
    int el = lane & 15, kg = lane >> 4;
    const float* src = edgeW + ((size_t)mt * 16 + el) * 96 + s * 32 + kg * 8 + jp * 2;
    ((unsigned*)eW_p)[q] = (unsigned)f2bf(src[0]) | ((unsigned)f2bf(src[1]) << 16);
  }
  for (int q = tid; q < 1024; q += 512) {  // gateW: f = mt
    int f = q >> 8, lane = (q >> 2) & 63, jp = q & 3;
    int el = lane & 15, kg = lane >> 4;
    const float* src = gateW + ((size_t)f * 16 + el) * 32 + kg * 8 + jp * 2;
    ((unsigned*)gW_p)[q] = (unsigned)f2bf(src[0]) | ((unsigned)f2bf(src[1]) << 16);
  }
  if (tid < 192) tb_s[tid] = theta_b[tid];
  if (tid < 64) {
    gb_s[tid] = gate_b[tid]; ns2_s[tid] = ns2[tid];
    nb2_s[tid] = nb2[tid];   nsh2_s[tid] = nsh2[tid];
  }
  if (tid < 32) {
    eb_s[tid] = edge_b[tid];
    ws1_s[tid] = ws1[tid]; wb1_s[tid] = wb1[tid]; wsh1_s[tid] = wsh1[tid];
    ws2_s[tid] = ws2[tid]; wb2_s[tid] = wb2[tid]; wsh2_s[tid] = wsh2[tid];
  }

  const int l  = tid & 63;
  const int wv = tid >> 6;
  const int el = l & 15;
  const int kg = l >> 4;

  // ---- wW1/wW2 fragments in registers ----
  bf16x8 w1f[2], w2f[2];
#pragma unroll
  for (int mt = 0; mt < 2; ++mt) {
    union { bf16x8 v; u16 u[8]; } a, bq;
    const float* s1 = wW1 + ((size_t)mt * 16 + el) * 32 + kg * 8;
    const float* s2 = wW2 + ((size_t)mt * 16 + el) * 32 + kg * 8;
#pragma unroll
    for (int j = 0; j < 8; ++j) { a.u[j] = f2bf(s1[j]); bq.u[j] = f2bf(s2[j]); }
    w1f[mt] = a.v; w2f[mt] = bq.v;
  }

  // ---- cooperative x-slab load: 32 nodes x 32 ch x 16 k, once, coalesced ----
  for (int q = tid; q < 4096; q += 512) {
    int ch = q >> 7, rem = q & 127, nl = rem >> 2, k4 = rem & 3;
    int nodeid = nbase + nl;
    int b = nodeid / N_;
    int n = nodeid - b * N_;
    float4 v = *(const float4*)&wfeat[(((size_t)b * 32 + ch) * N_ + n) * 16 + k4 * 4];
    slab[SL(nl, k4 * 4 + 0, ch)] = f2bf(v.x);
    slab[SL(nl, k4 * 4 + 1, ch)] = f2bf(v.y);
    slab[SL(nl, k4 * 4 + 2, ch)] = f2bf(v.z);
    slab[SL(nl, k4 * 4 + 3, ch)] = f2bf(v.w);
  }
  __syncthreads();

  const f32x4 z4 = {0.f, 0.f, 0.f, 0.f};

  // ================= phase 1: per-wave node loop =================
  for (int it = 0; it < 4; ++it) {
    const int nl = it * 8 + wv;
    const int nodeid = nbase + nl;
    const int b = nodeid / N_;
    const int ebase = nodeid * 16;

    const int idx = nn_idx[ebase + el];
    const int et  = etype[ebase + el];

    // nb B-fragments straight from gather
    const bf16x8* nbp = (const bf16x8*)(nf1b + (((size_t)b * N_ + idx) * 64 + kg * 8));
    bf16x8 nbf0 = nbp[0];
    bf16x8 nbf1 = nbp[4];

    // x B-frag from slab
    bf16x8 xv = *(const bf16x8*)&slab[SL(nl, el, kg * 8)];

    // wf1 = relu(bn(wW1 @ x))
    f32x4 wc[2];
#pragma unroll
    for (int mt = 0; mt < 2; ++mt)
      wc[mt] = __builtin_amdgcn_mfma_f32_16x16x32_bf16(w1f[mt], xv, z4, 0, 0, 0);
#pragma unroll
    for (int mt = 0; mt < 2; ++mt) {
      int ob = mt * 16 + kg * 4;
      float4 s  = *(const float4*)&ws1_s[ob];
      float4 bb = *(const float4*)&wb1_s[ob];
      float4 sh = *(const float4*)&wsh1_s[ob];
      uint2 d;
      d.x = (unsigned)f2bf(fmaxf(fmaf(s.x, wc[mt][0] + bb.x, sh.x), 0.f)) |
            ((unsigned)f2bf(fmaxf(fmaf(s.y, wc[mt][1] + bb.y, sh.y), 0.f)) << 16);
      d.y = (unsigned)f2bf(fmaxf(fmaf(s.z, wc[mt][2] + bb.z, sh.z), 0.f)) |
            ((unsigned)f2bf(fmaxf(fmaf(s.w, wc[mt][3] + bb.w, sh.w), 0.f)) << 16);
      *(uint2*)&slab[SL(nl, el, ob)] = d;  // overwrite x[nl] (fully consumed)
    }
    bf16x8 wff = *(const bf16x8*)&slab[SL(nl, el, kg * 8)];

    // msg: 24 MFMAs, etype mask folded into B
    f32x4 macc[4] = {z4, z4, z4, z4};
    union U { bf16x8 v; uint4 q; } nb0u, nb1u;
    nb0u.v = nbf0; nb1u.v = nbf1;
#pragma unroll
    for (int t = 0; t < 3; ++t) {
      unsigned msk = (et == t) ? 0xffffffffu : 0u;
      union U b0, b1;
      b0.q.x = nb0u.q.x & msk; b0.q.y = nb0u.q.y & msk;
      b0.q.z = nb0u.q.z & msk; b0.q.w = nb0u.q.w & msk;
      b1.q.x = nb1u.q.x & msk; b1.q.y = nb1u.q.y & msk;
      b1.q.z = nb1u.q.z & msk; b1.q.w = nb1u.q.w & msk;
#pragma unroll
      for (int mt = 0; mt < 4; ++mt) {
        bf16x8 a0 = *(const bf16x8*)&th_p[((t * 8 + mt * 2 + 0) * 64 + l) * 8];
        bf16x8 a1 = *(const bf16x8*)&th_p[((t * 8 + mt * 2 + 1) * 64 + l) * 8];
        macc[mt] = __builtin_amdgcn_mfma_f32_16x16x32_bf16(a0, b0.v, macc[mt], 0, 0, 0);
        macc[mt] = __builtin_amdgcn_mfma_f32_16x16x32_bf16(a1, b1.v, macc[mt], 0, 0, 0);
      }
    }

    // edge conv: edgeW @ [wf1; nb]
    f32x4 eacc[2];
#pragma unroll
    for (int mt = 0; mt < 2; ++mt) {
      bf16x8 a0 = *(const bf16x8*)&eW_p[((mt * 3 + 0) * 64 + l) * 8];
      bf16x8 a1 = *(const bf16x8*)&eW_p[((mt * 3 + 1) * 64 + l) * 8];
      bf16x8 a2 = *(const bf16x8*)&eW_p[((mt * 3 + 2) * 64 + l) * 8];
      f32x4 acc = __builtin_amdgcn_mfma_f32_16x16x32_bf16(a0, wff, z4, 0, 0, 0);
      acc = __builtin_amdgcn_mfma_f32_16x16x32_bf16(a1, nbf0, acc, 0, 0, 0);
      acc = __builtin_amdgcn_mfma_f32_16x16x32_bf16(a2, nbf1, acc, 0, 0, 0);
      eacc[mt] = acc;
    }

    // gate + combine + mean over edges -> nout_s
#pragma unroll
    for (int mt = 0; mt < 4; ++mt) {
      bf16x8 ga = *(const bf16x8*)&gW_p[(mt * 64 + l) * 8];
      f32x4 g = __builtin_amdgcn_mfma_f32_16x16x32_bf16(ga, wff, z4, 0, 0, 0);
      int ob = mt * 16 + kg * 4;
      float4 tb = *(const float4*)&tb_s[et * 64 + ob];
      float4 gb = *(const float4*)&gb_s[ob];
      float p0 = (macc[mt][0] + tb.x) * sigm(g[0] + gb.x);
      float p1 = (macc[mt][1] + tb.y) * sigm(g[1] + gb.y);
      float p2 = (macc[mt][2] + tb.z) * sigm(g[2] + gb.z);
      float p3 = (macc[mt][3] + tb.w) * sigm(g[3] + gb.w);
#pragma unroll
      for (int sft = 1; sft < 16; sft <<= 1) {
        p0 += __shfl_xor(p0, sft);
        p1 += __shfl_xor(p1, sft);
        p2 += __shfl_xor(p2, sft);
        p3 += __shfl_xor(p3, sft);
      }
      if (el == 0) {
        float4 r4;
        r4.x = fmaxf(p0 * 0.0625f, 0.f);
        r4.y = fmaxf(p1 * 0.0625f, 0.f);
        r4.z = fmaxf(p2 * 0.0625f, 0.f);
        r4.w = fmaxf(p3 * 0.0625f, 0.f);
        *(float4*)&nout_s[nl * 68 + ob] = r4;
      }
    }

    // w_out = relu(edge + eb) -> slab (overwrites wf1 tile)
#pragma unroll
    for (int mt = 0; mt < 2; ++mt) {
      int ob = mt * 16 + kg * 4;
      float4 eb4 = *(const float4*)&eb_s[ob];
      uint2 d;
      d.x = (unsigned)f2bf(fmaxf(eacc[mt][0] + eb4.x, 0.f)) |
            ((unsigned)f2bf(fmaxf(eacc[mt][1] + eb4.y, 0.f)) << 16);
      d.y = (unsigned)f2bf(fmaxf(eacc[mt][2] + eb4.z, 0.f)) |
            ((unsigned)f2bf(fmaxf(eacc[mt][3] + eb4.w, 0.f)) << 16);
      *(uint2*)&slab[SL(nl, el, ob)] = d;
    }
    bf16x8 wof = *(const bf16x8*)&slab[SL(nl, el, kg * 8)];

    // wf2 pre-residual = relu(bn(wW2 @ w_out)) -> slab (bf16)
    f32x4 fc[2];
#pragma unroll
    for (int mt = 0; mt < 2; ++mt)
      fc[mt] = __builtin_amdgcn_mfma_f32_16x16x32_bf16(w2f[mt], wof, z4, 0, 0, 0);
#pragma unroll
    for (int mt = 0; mt < 2; ++mt) {
      int ob = mt * 16 + kg * 4;
      float4 s  = *(const float4*)&ws2_s[ob];
      float4 bb = *(const float4*)&wb2_s[ob];
      float4 sh = *(const float4*)&wsh2_s[ob];
      uint2 d;
      d.x = (unsigned)f2bf(fmaxf(fmaf(s.x, fc[mt][0] + bb.x, sh.x), 0.f)) |
            ((unsigned)f2bf(fmaxf(fmaf(s.y, fc[mt][1] + bb.y, sh.y), 0.f)) << 16);
      d.y = (unsigned)f2bf(fmaxf(fmaf(s.z, fc[mt][2] + bb.z, sh.z), 0.f)) |
            ((unsigned)f2bf(fmaxf(fmaf(s.w, fc[mt][3] + bb.w, sh.w), 0.f)) << 16);
      *(uint2*)&slab[SL(nl, el, ob)] = d;
    }
  }
  __syncthreads();

  // ================= phase 2: nf2 + node residual, coalesced =================
  {
    const int nl2 = tid & 31;
    const int c0  = tid >> 5;
    const int nodeid = nbase + nl2;
    const int b2 = nodeid / N_;
    const int n2 = nodeid - b2 * N_;
    const float* nrow = &nout_s[nl2 * 68];
#pragma unroll
    for (int pp = 0; pp < 4; ++pp) {
      int c = pp * 16 + c0;
      const float* wrow = nW2 + (size_t)c * 64;
      float acc = 0.f;
#pragma unroll
      for (int c2 = 0; c2 < 64; c2 += 4) {
        float4 w4 = *(const float4*)&wrow[c2];
        acc = fmaf(w4.x, nrow[c2 + 0], acc);
        acc = fmaf(w4.y, nrow[c2 + 1], acc);
        acc = fmaf(w4.z, nrow[c2 + 2], acc);
        acc = fmaf(w4.w, nrow[c2 + 3], acc);
      }
      size_t off = ((size_t)b2 * 64 + c) * N_ + n2;
      float y = fmaxf(fmaf(ns2_s[c], acc + nb2_s[c], nsh2_s[c]), 0.f);
      out_nf[off] = y + node[off];
    }
  }

  // ================= phase 3: wf2 residual + coalesced store =================
  {
    const int nl3 = tid & 31;
    const int ch0 = tid >> 5;
    const int nodeid = nbase + nl3;
    const int b3 = nodeid / N_;
    const int n3 = nodeid - b3 * N_;
#pragma unroll
    for (int pp = 0; pp < 2; ++pp) {
      int ch = pp * 16 + ch0;
      size_t gbase = (((size_t)b3 * 32 + ch) * N_ + n3) * 16;
      float v[16];
#pragma unroll
      for (int k = 0; k < 16; ++k) v[k] = bf2f(slab[SL(nl3, k, ch)]);
      const float4* wr = (const float4*)&wfeat[gbase];
      float4 r0 = wr[0], r1 = wr[1], r2 = wr[2], r3 = wr[3];
      float4 o0 = {v[0] + r0.x,  v[1] + r0.y,  v[2] + r0.z,  v[3] + r0.w};
      float4 o1 = {v[4] + r1.x,  v[5] + r1.y,  v[6] + r1.z,  v[7] + r1.w};
      float4 o2 = {v[8] + r2.x,  v[9] + r2.y,  v[10] + r2.z, v[11] + r2.w};
      float4 o3 = {v[12] + r3.x, v[13] + r3.y, v[14] + r3.z, v[15] + r3.w};
      float4* op = (float4*)&out_wf[gbase];
      op[0] = o0; op[1] = o1; op[2] = o2; op[3] = o3;
    }
  }
}

extern "C" void kernel_launch(void* const* d_in, const int* in_sizes, int n_in,
                              void* d_out, int out_size, void* d_ws, size_t ws_size,
                              hipStream_t stream) {
  const float* node    = (const float*)d_in[0];
  const float* wfeat   = (const float*)d_in[1];
  const int*   etype   = (const int*)d_in[2];
  const int*   nn_idx  = (const int*)d_in[3];
  const float* nW1     = (const float*)d_in[4];
  const float* nb1     = (const float*)d_in[5];
  const float* ns1     = (const float*)d_in[6];
  const float* nsh1    = (const float*)d_in[7];
  const float* wW1     = (const float*)d_in[8];
  const float* wb1     = (const float*)d_in[9];
  const float* ws1     = (const float*)d_in[10];
  const float* wsh1    = (const float*)d_in[11];
  const float* theta   = (const float*)d_in[12];
  const float* theta_b = (const float*)d_in[13];
  const float* gateW   = (const float*)d_in[14];
  const float* gate_b  = (const float*)d_in[15];
  const float* edgeW   = (const float*)d_in[16];
  const float* edge_b  = (const float*)d_in[17];
  const float* nW2     = (const float*)d_in[18];
  const float* nb2     = (const float*)d_in[19];
  const float* ns2     = (const float*)d_in[20];
  const float* nsh2    = (const float*)d_in[21];
  const float* wW2     = (const float*)d_in[22];
  const float* wb2     = (const float*)d_in[23];
  const float* ws2     = (const float*)d_in[24];
  const float* wsh2    = (const float*)d_in[25];

  u16*   nf1b   = (u16*)d_ws;                           // 40000*64 bf16 = 5.12 MB
  float* out_nf = (float*)d_out;                        // (B,64,N,1)
  float* out_wf = (float*)d_out + (size_t)B_ * 64 * N_; // (B,32,N,16)

  k_nf1<<<625, 256, 0, stream>>>(node, nW1, nb1, ns1, nsh1, nf1b);
  k_fused<<<1250, 512, 0, stream>>>(node, wfeat, etype, nn_idx, nf1b,
                                    wW1, wb1, ws1, wsh1,
                                    theta, theta_b, gateW, gate_b, edgeW, edge_b,
                                    nW2, nb2, ns2, nsh2, wW2, wb2, ws2, wsh2,
                                    out_nf, out_wf);
}